// Round 3
// baseline (414.764 us; speedup 1.0000x reference)
//
#include <hip/hip_runtime.h>
#include <cmath>

#define BATCH 32
#define SEQLEN 512
#define NSAMP 1000
#define DMODEL 1024
#define NCHUNK 4

typedef __bf16 bf16x8_t __attribute__((ext_vector_type(8)));
typedef float f32x4_t __attribute__((ext_vector_type(4)));

__device__ __forceinline__ unsigned pack_bf2(float lo, float hi) {
    unsigned ulo = __float_as_uint(lo);
    unsigned uhi = __float_as_uint(hi);
    ulo = (ulo + 0x7fffu + ((ulo >> 16) & 1u)) >> 16;
    uhi = (uhi + 0x7fffu + ((uhi >> 16) & 1u)) & 0xffff0000u;
    return (ulo & 0xffffu) | uhi;
}

// TF log-uniform sampler expected-count, log-domain
__device__ __forceinline__ float log_expected_count(int id) {
    float idf = (float)id;
    float p = log1pf(1.0f / (idf + 1.0f)) * 0.09242316f; // 1/ln(50001)
    return logf(-expm1f(1000.0f * log1pf(-p)));
}

// async 16B global->LDS (dest = wave-uniform base + lane*16)
__device__ __forceinline__ void gl16(const void* g, void* l) {
    __builtin_amdgcn_global_load_lds(
        (const __attribute__((address_space(1))) unsigned int*)g,
        (__attribute__((address_space(3))) unsigned int*)l,
        16, 0, 0);
}

// ---- prep: W-row gather->bf16 (+adj), fp32 true-logit dot, and h->bf16 ----
__global__ __launch_bounds__(256) void prep_kernel(
    const float* __restrict__ h, const int* __restrict__ labels,
    const int* __restrict__ sids, const float* __restrict__ W,
    const float* __restrict__ bias, unsigned short* __restrict__ Wb,
    unsigned short* __restrict__ hb,
    float* __restrict__ adjw, float* __restrict__ tlw)
{
    const int w = threadIdx.x >> 6, lane = threadIdx.x & 63;
    if (blockIdx.x < 8000) {
        const int row = blockIdx.x * 4 + w;            // b*1000+s
        const int sv = sids[row];
        const float4* src = (const float4*)(W + (size_t)sv * DMODEL);
        unsigned short* dst = Wb + (size_t)row * DMODEL;
#pragma unroll
        for (int j = 0; j < 4; ++j) {
            float4 v = src[lane + j * 64];
            uint2 u;
            u.x = pack_bf2(v.x, v.y);
            u.y = pack_bf2(v.z, v.w);
            *(uint2*)(dst + (lane + j * 64) * 4) = u;
        }
        if (lane == 0) adjw[row] = bias[sv] - log_expected_count(sv);
    } else {
        const int r = (blockIdx.x - 8000) * 4 + w;     // b*512+t
        const int lab = labels[r];
        const float4* hp = (const float4*)(h + (size_t)r * DMODEL);
        const float4* wp = (const float4*)(W + (size_t)lab * DMODEL);
        unsigned short* hdst = hb + (size_t)r * DMODEL;
        float s = 0.0f;
#pragma unroll
        for (int j = 0; j < 4; ++j) {
            float4 a = hp[lane + j * 64];
            float4 c = wp[lane + j * 64];
            s += a.x * c.x + a.y * c.y + a.z * c.z + a.w * c.w;
            uint2 u;
            u.x = pack_bf2(a.x, a.y);
            u.y = pack_bf2(a.z, a.w);
            *(uint2*)(hdst + (lane + j * 64) * 4) = u;
        }
#pragma unroll
        for (int off = 32; off > 0; off >>= 1) s += __shfl_xor(s, off, 64);
        if (lane == 0) tlw[r] = s + bias[lab] - log_expected_count(lab);
    }
}

// ---- main: 64x256 tile, BK=32, 3-buffer depth-2 pipeline, counted vmcnt ----
// Grid: 1D 1024, XCD-locality remap. All 32 blocks of one bb (8 tile_t x
// 4 chunk) land on ONE XCD consecutively: per-bb working set = hb(bb) 1MB +
// Wb(bb) 2MB = 3MB fits the 4MB XCD L2, so the 8x B-panel / 4x A-panel
// re-reads become L2 hits instead of HBM fetches.
__global__ __launch_bounds__(256, 2) void sampled_softmax_main(
    const int* __restrict__ labels, const int* __restrict__ sids,
    const unsigned short* __restrict__ hb, const unsigned short* __restrict__ Wb,
    const float* __restrict__ adjw,
    float* __restrict__ pm, float* __restrict__ pl)
{
    __shared__ __align__(16) unsigned short Ab[3][64 * 32];    // 12 KB
    __shared__ __align__(16) unsigned short Bb[3][256 * 32];   // 48 KB
    __shared__ int   sid_lds[256];
    __shared__ float adj_lds[256];
    __shared__ int   lab_lds[64];
    __shared__ float mpart[4][64];
    __shared__ float lpart[4][64];

    // bijective XCD-aware decode: wg = xcd + 8*(gslot*32 + inner)
    const int wg     = blockIdx.x;       // 0..1023
    const int xcd    = wg & 7;
    const int seq    = wg >> 3;          // 0..127 (dispatch order on this XCD)
    const int bb     = xcd + 8 * (seq >> 5);   // 0..31, one bb per 32-block run
    const int inner  = seq & 31;
    const int tile_t = inner & 7;        // 0..7
    const int chunk  = inner >> 3;       // 0..3
    const int t0  = tile_t * 64;
    const int tid = threadIdx.x;
    const int w   = tid >> 6, l = tid & 63;
    const int lm  = l & 15,   q = l >> 4;
    const int rl4 = l >> 2,  cp = l & 3;

    {   // block-level index/adj staging (read only in epilogue)
        const int s = chunk * 256 + tid;
        const bool v = s < NSAMP;
        sid_lds[tid] = v ? sids[bb * NSAMP + s] : -1;
        adj_lds[tid] = v ? adjw[bb * NSAMP + s] : 0.0f;
        if (tid < 64) lab_lds[tid] = labels[bb * SEQLEN + t0 + tid];
    }

    // staging: linear LDS dest, inverse-swizzled global source (rule #21)
    // swizzle s(r) = (r&3)^((r>>2)&3) -> 2-way (free) on frag ds_read_b128
    const int swzs = (rl4 & 3) ^ ((rl4 >> 2) & 3);
    const int cs = (cp ^ swzs) * 8;                    // element offset in 32-wide row
    const unsigned short* aS = hb + (size_t)(bb * SEQLEN + t0 + 16 * w + rl4) * DMODEL + cs;
    const unsigned short* bS[4];
#pragma unroll
    for (int j = 0; j < 4; ++j) {
        int rb = chunk * 256 + 64 * w + 16 * j + rl4;
        if (rb > NSAMP - 1) rb = NSAMP - 1;            // clamp (masked in LSE)
        bS[j] = Wb + (size_t)(bb * NSAMP + rb) * DMODEL + cs;
    }

#define STAGE_TILE(KT, BUF)                                                   \
    do {                                                                      \
        const int _adv = (KT) * 32;                                           \
        gl16(aS + _adv, &Ab[BUF][(16 * w) * 32]);                             \
        gl16(bS[0] + _adv, &Bb[BUF][(64 * w) * 32]);                          \
        gl16(bS[1] + _adv, &Bb[BUF][(64 * w + 16) * 32]);                     \
        gl16(bS[2] + _adv, &Bb[BUF][(64 * w + 32) * 32]);                     \
        gl16(bS[3] + _adv, &Bb[BUF][(64 * w + 48) * 32]);                     \
    } while (0)

    // fragment read offsets (swizzled)
    const int fswz = (lm & 3) ^ ((lm >> 2) & 3);
    const int fp = (q ^ fswz) * 8;
    int aoff[4], boff[4];
#pragma unroll
    for (int t = 0; t < 4; ++t) aoff[t] = (16 * t + lm) * 32 + fp;
#pragma unroll
    for (int c = 0; c < 4; ++c) boff[c] = (64 * w + 16 * c + lm) * 32 + fp;

    f32x4_t acc[4][4];
#pragma unroll
    for (int t = 0; t < 4; ++t)
#pragma unroll
        for (int c = 0; c < 4; ++c) acc[t][c] = (f32x4_t){0.f, 0.f, 0.f, 0.f};

    // prologue: tiles 0 and 1 in flight (10 loads/wave), no vm drain.
    STAGE_TILE(0, 0);
    STAGE_TILE(1, 1);
    // make sid/adj/lab ds_writes visible; lgkmcnt does NOT touch vmcnt.
    asm volatile("s_waitcnt lgkmcnt(0)" ::: "memory");
    __builtin_amdgcn_s_barrier();

#pragma unroll
    for (int kt = 0; kt < 32; ++kt) {
        if (kt < 31) { asm volatile("s_waitcnt vmcnt(5)" ::: "memory"); }
        else         { asm volatile("s_waitcnt vmcnt(0)" ::: "memory"); }
        __builtin_amdgcn_s_barrier();
        // stage(kt+2): overwrites buf[(kt-1)%3]; all waves consumed it
        // (their ds_reads fed MFMAs before arriving at this barrier).
        if (kt + 2 < 32) STAGE_TILE(kt + 2, (kt + 2) % 3);

        const unsigned short* Ac = Ab[kt % 3];
        const unsigned short* Bc = Bb[kt % 3];
        bf16x8_t fa[4];
#pragma unroll
        for (int t = 0; t < 4; ++t) fa[t] = *(const bf16x8_t*)(Ac + aoff[t]);
        bf16x8_t fb[4];
#pragma unroll
        for (int c = 0; c < 4; ++c) fb[c] = *(const bf16x8_t*)(Bc + boff[c]);
        __builtin_amdgcn_s_setprio(1);
#pragma unroll
        for (int c = 0; c < 4; ++c)
#pragma unroll
            for (int t = 0; t < 4; ++t)
                acc[t][c] = __builtin_amdgcn_mfma_f32_16x16x32_bf16(fa[t], fb[c], acc[t][c], 0, 0, 0);
        __builtin_amdgcn_s_setprio(0);
    }
#undef STAGE_TILE

    // epilogue: in-register partial LSE.
    // C layout: row = 16*t + 4*q + i, col = 64*w + 16*c + lm
    float adjv[4]; int sidv[4]; bool cval[4];
#pragma unroll
    for (int c = 0; c < 4; ++c) {
        const int col = 64 * w + 16 * c + lm;
        adjv[c] = adj_lds[col];
        sidv[c] = sid_lds[col];
        cval[c] = (chunk * 256 + col) < NSAMP;
    }
#pragma unroll
    for (int t = 0; t < 4; ++t) {
#pragma unroll
        for (int i = 0; i < 4; ++i) {
            const int r = 16 * t + 4 * q + i;
            const int lab = lab_lds[r];
            float x[4]; bool ok[4];
            float m = -INFINITY;
#pragma unroll
            for (int c = 0; c < 4; ++c) {
                x[c] = acc[t][c][i] + adjv[c];
                ok[c] = cval[c] && (sidv[c] != lab);
                if (ok[c]) m = fmaxf(m, x[c]);
            }
            float ls = 0.0f;
#pragma unroll
            for (int c = 0; c < 4; ++c) ls += ok[c] ? __expf(x[c] - m) : 0.0f;
            // merge (m,l) across the 16 lanes holding this row's columns
#pragma unroll
            for (int off = 1; off < 16; off <<= 1) {
                const float mo = __shfl_xor(m, off, 64);
                const float lo = __shfl_xor(ls, off, 64);
                const float M  = fmaxf(m, mo);
                const float e1 = (ls > 0.0f) ? ls * __expf(m - M) : 0.0f;
                const float e2 = (lo > 0.0f) ? lo * __expf(mo - M) : 0.0f;
                m = M; ls = e1 + e2;
            }
            if (lm == 0) { mpart[w][r] = m; lpart[w][r] = ls; }
        }
    }
    __syncthreads();
    if (tid < 64) {
        float m = -INFINITY, lsum = 0.0f;
#pragma unroll
        for (int p = 0; p < 4; ++p) {
            const float mp = mpart[p][tid];
            const float lp = lpart[p][tid];
            if (lp > 0.0f) {
                if (mp > m) { lsum = lsum * __expf(m - mp) + lp; m = mp; }
                else        { lsum += lp * __expf(mp - m); }
            }
        }
        const int idx = (bb * SEQLEN + t0 + tid) * NCHUNK + chunk;
        pm[idx] = m;
        pl[idx] = lsum;
    }
}

// ---- combine: merge 4 partial (m,l) + true logit -> per-block loss sums ----
__global__ __launch_bounds__(256) void combine_kernel(
    const float* __restrict__ pm, const float* __restrict__ pl,
    const float* __restrict__ tlw, float* __restrict__ bsum)
{
    __shared__ float wsum[4];
    const int tid = threadIdx.x;
    const int w = tid >> 6, lane = tid & 63;
    const int idx = blockIdx.x * 256 + tid;      // 0..16383
    float m = -INFINITY, l = 0.0f;
#pragma unroll
    for (int c = 0; c < NCHUNK; ++c) {
        const float mp = pm[idx * NCHUNK + c];
        const float lp = pl[idx * NCHUNK + c];
        if (lp > 0.0f) {
            if (mp > m) { l = l * __expf(m - mp) + lp; m = mp; }
            else        { l += lp * __expf(mp - m); }
        }
    }
    const float t = tlw[idx];
    const float M = fmaxf(m, t);
    float loss = __logf(l * __expf(m - M) + __expf(t - M)) + M - t;
#pragma unroll
    for (int off = 32; off > 0; off >>= 1) loss += __shfl_xor(loss, off, 64);
    if (lane == 0) wsum[w] = loss;
    __syncthreads();
    if (tid == 0) bsum[blockIdx.x] = wsum[0] + wsum[1] + wsum[2] + wsum[3];
}

__global__ void finalize_kernel(const float* __restrict__ bsum, float* __restrict__ out) {
    float v = bsum[threadIdx.x];
#pragma unroll
    for (int off = 32; off > 0; off >>= 1) v += __shfl_xor(v, off, 64);
    if (threadIdx.x == 0) out[0] = v * (0.5f / (float)(BATCH * SEQLEN));
}

extern "C" void kernel_launch(void* const* d_in, const int* in_sizes, int n_in,
                              void* d_out, int out_size, void* d_ws, size_t ws_size,
                              hipStream_t stream) {
    const float* h      = (const float*)d_in[0];
    const int*   labels = (const int*)d_in[1];
    const int*   sids   = (const int*)d_in[2];
    const float* W      = (const float*)d_in[3];
    const float* bias   = (const float*)d_in[4];

    // workspace layout (~99.8 MB, 16B-aligned offsets)
    char* base = (char*)d_ws;
    unsigned short* Wb = (unsigned short*)base;                 // 65,536,000
    unsigned short* hb = (unsigned short*)(base + 65536000);    // 33,554,432
    float* adjw = (float*)(base + 99090432);                    //    128,000
    float* tlw  = (float*)(base + 99218432);                    //     65,536
    float* pmw  = (float*)(base + 99283968);                    //    262,144
    float* plw  = (float*)(base + 99546112);                    //    262,144
    float* bsum = (float*)(base + 99808256);                    //        256

    prep_kernel<<<dim3(12096), dim3(256), 0, stream>>>(h, labels, sids, W, bias, Wb, hb, adjw, tlw);
    sampled_softmax_main<<<dim3(1024), dim3(256), 0, stream>>>(
        labels, sids, hb, Wb, adjw, pmw, plw);
    combine_kernel<<<dim3(64), dim3(256), 0, stream>>>(pmw, plw, tlw, bsum);
    finalize_kernel<<<dim3(1), dim3(64), 0, stream>>>(bsum, (float*)d_out);
}

// Round 4
// 394.786 us; speedup vs baseline: 1.0506x; 1.0506x over previous
//
#include <hip/hip_runtime.h>
#include <cmath>

#define BATCH 32
#define SEQLEN 512
#define NSAMP 1000
#define DMODEL 1024
#define NCHUNK 4

typedef __bf16 bf16x8_t __attribute__((ext_vector_type(8)));
typedef float f32x4_t __attribute__((ext_vector_type(4)));

__device__ __forceinline__ unsigned pack_bf2(float lo, float hi) {
    unsigned ulo = __float_as_uint(lo);
    unsigned uhi = __float_as_uint(hi);
    ulo = (ulo + 0x7fffu + ((ulo >> 16) & 1u)) >> 16;
    uhi = (uhi + 0x7fffu + ((uhi >> 16) & 1u)) & 0xffff0000u;
    return (ulo & 0xffffu) | uhi;
}

// TF log-uniform sampler expected-count, log-domain
__device__ __forceinline__ float log_expected_count(int id) {
    float idf = (float)id;
    float p = log1pf(1.0f / (idf + 1.0f)) * 0.09242316f; // 1/ln(50001)
    return logf(-expm1f(1000.0f * log1pf(-p)));
}

// async 16B global->LDS (dest = wave-uniform base + lane*16)
__device__ __forceinline__ void gl16(const void* g, void* l) {
    __builtin_amdgcn_global_load_lds(
        (const __attribute__((address_space(1))) unsigned int*)g,
        (__attribute__((address_space(3))) unsigned int*)l,
        16, 0, 0);
}

// ---- prep: W-row gather->bf16 (+adj), fp32 true-logit dot, and h->bf16 ----
__global__ __launch_bounds__(256) void prep_kernel(
    const float* __restrict__ h, const int* __restrict__ labels,
    const int* __restrict__ sids, const float* __restrict__ W,
    const float* __restrict__ bias, unsigned short* __restrict__ Wb,
    unsigned short* __restrict__ hb,
    float* __restrict__ adjw, float* __restrict__ tlw)
{
    const int w = threadIdx.x >> 6, lane = threadIdx.x & 63;
    if (blockIdx.x < 8000) {
        const int row = blockIdx.x * 4 + w;            // b*1000+s
        const int sv = sids[row];
        const float4* src = (const float4*)(W + (size_t)sv * DMODEL);
        unsigned short* dst = Wb + (size_t)row * DMODEL;
#pragma unroll
        for (int j = 0; j < 4; ++j) {
            float4 v = src[lane + j * 64];
            uint2 u;
            u.x = pack_bf2(v.x, v.y);
            u.y = pack_bf2(v.z, v.w);
            *(uint2*)(dst + (lane + j * 64) * 4) = u;
        }
        if (lane == 0) adjw[row] = bias[sv] - log_expected_count(sv);
    } else {
        const int r = (blockIdx.x - 8000) * 4 + w;     // b*512+t
        const int lab = labels[r];
        const float4* hp = (const float4*)(h + (size_t)r * DMODEL);
        const float4* wp = (const float4*)(W + (size_t)lab * DMODEL);
        unsigned short* hdst = hb + (size_t)r * DMODEL;
        float s = 0.0f;
#pragma unroll
        for (int j = 0; j < 4; ++j) {
            float4 a = hp[lane + j * 64];
            float4 c = wp[lane + j * 64];
            s += a.x * c.x + a.y * c.y + a.z * c.z + a.w * c.w;
            uint2 u;
            u.x = pack_bf2(a.x, a.y);
            u.y = pack_bf2(a.z, a.w);
            *(uint2*)(hdst + (lane + j * 64) * 4) = u;
        }
#pragma unroll
        for (int off = 32; off > 0; off >>= 1) s += __shfl_xor(s, off, 64);
        if (lane == 0) tlw[r] = s + bias[lab] - log_expected_count(lab);
    }
}

// ---- main: 256x256 tile, BK=32, 8 waves (2x4), depth-2 counted-vmcnt ----
// Traffic: A read 4x (134 MB) + B read 2x (131 MB) = 265 MB, vs 670 MB at
// the old 64x256 tile. grid = 256 blocks = 1/CU; bb = wg&31 keeps all 8
// blocks of one bb on one XCD (wg%8 == bb%8).
__global__ __launch_bounds__(512, 2) void sampled_softmax_main(
    const int* __restrict__ labels, const int* __restrict__ sids,
    const unsigned short* __restrict__ hb, const unsigned short* __restrict__ Wb,
    const float* __restrict__ adjw,
    float* __restrict__ pm, float* __restrict__ pl)
{
    __shared__ __align__(16) unsigned short Ab[3][256 * 32];   // 48 KB
    __shared__ __align__(16) unsigned short Bb[3][256 * 32];   // 48 KB
    __shared__ int   sid_lds[256];
    __shared__ float adj_lds[256];
    __shared__ int   lab_lds[256];
    __shared__ float mpart[4][256];
    __shared__ float lpart[4][256];

    const int wg     = blockIdx.x;       // 0..255
    const int bb     = wg & 31;          // same-bb blocks share XCD (wg%8)
    const int rest   = wg >> 5;          // 0..7
    const int tile_t = rest & 1;         // 0..1
    const int chunk  = rest >> 1;        // 0..3
    const int t0  = tile_t * 256;
    const int tid = threadIdx.x;
    const int wv  = tid >> 6, l = tid & 63;
    const int wr  = wv >> 2, wc = wv & 3;   // 2x4 wave grid
    const int lm  = l & 15,  q = l >> 4;
    const int rl4 = l >> 2,  cp = l & 3;

    if (tid < 256) {   // block-level index/adj staging (read only in epilogue)
        const int s = chunk * 256 + tid;
        const bool v = s < NSAMP;
        sid_lds[tid] = v ? sids[bb * NSAMP + s] : -1;
        adj_lds[tid] = v ? adjw[bb * NSAMP + s] : 0.0f;
        lab_lds[tid] = labels[bb * SEQLEN + t0 + tid];
    }

    // staging: linear LDS dest, inverse-swizzled global source (rule #21)
    // swizzle s(r) = (r&3)^((r>>2)&3) -> 2-way (free) on frag ds_read_b128
    const int swzs = (rl4 & 3) ^ ((rl4 >> 2) & 3);
    const int cs = (cp ^ swzs) * 8;                    // element offset in 32-wide row
    const unsigned short* aS0 = hb + (size_t)(bb * SEQLEN + t0 + 32 * wv + rl4) * DMODEL + cs;
    const unsigned short* aS1 = aS0 + (size_t)16 * DMODEL;
    int rb0 = chunk * 256 + 32 * wv + rl4;
    int rb1 = rb0 + 16;
    if (rb0 > NSAMP - 1) rb0 = NSAMP - 1;              // clamp (masked in LSE)
    if (rb1 > NSAMP - 1) rb1 = NSAMP - 1;
    const unsigned short* bS0 = Wb + (size_t)(bb * NSAMP + rb0) * DMODEL + cs;
    const unsigned short* bS1 = Wb + (size_t)(bb * NSAMP + rb1) * DMODEL + cs;

#define STAGE_TILE(KT, BUF)                                                   \
    do {                                                                      \
        const int _adv = (KT) * 32;                                           \
        gl16(aS0 + _adv, &Ab[BUF][(32 * wv) * 32]);                           \
        gl16(aS1 + _adv, &Ab[BUF][(32 * wv + 16) * 32]);                      \
        gl16(bS0 + _adv, &Bb[BUF][(32 * wv) * 32]);                           \
        gl16(bS1 + _adv, &Bb[BUF][(32 * wv + 16) * 32]);                      \
    } while (0)

    // fragment read offsets (swizzled); per-wave output 128 rows x 64 cols
    const int fswz = (lm & 3) ^ ((lm >> 2) & 3);
    const int fp = (q ^ fswz) * 8;
    int aoff[8], boff[4];
#pragma unroll
    for (int t = 0; t < 8; ++t) aoff[t] = (128 * wr + 16 * t + lm) * 32 + fp;
#pragma unroll
    for (int c = 0; c < 4; ++c) boff[c] = (64 * wc + 16 * c + lm) * 32 + fp;

    f32x4_t acc[8][4];
#pragma unroll
    for (int t = 0; t < 8; ++t)
#pragma unroll
        for (int c = 0; c < 4; ++c) acc[t][c] = (f32x4_t){0.f, 0.f, 0.f, 0.f};

    // prologue: tiles 0 and 1 in flight (8 loads/thread), no vm drain.
    STAGE_TILE(0, 0);
    STAGE_TILE(1, 1);
    // make sid/adj/lab ds_writes visible; lgkmcnt does NOT touch vmcnt.
    asm volatile("s_waitcnt lgkmcnt(0)" ::: "memory");
    __builtin_amdgcn_s_barrier();

#pragma unroll
    for (int kt = 0; kt < 32; ++kt) {
        if (kt < 31) { asm volatile("s_waitcnt vmcnt(4)" ::: "memory"); }
        else         { asm volatile("s_waitcnt vmcnt(0)" ::: "memory"); }
        __builtin_amdgcn_s_barrier();
        // stage(kt+2): overwrites buf[(kt-1)%3]; all waves consumed it
        // (their ds_reads fed MFMAs before arriving at this barrier).
        if (kt + 2 < 32) STAGE_TILE(kt + 2, (kt + 2) % 3);

        const unsigned short* Ac = Ab[kt % 3];
        const unsigned short* Bc = Bb[kt % 3];
        bf16x8_t fa[8];
#pragma unroll
        for (int t = 0; t < 8; ++t) fa[t] = *(const bf16x8_t*)(Ac + aoff[t]);
        __builtin_amdgcn_s_setprio(1);
#pragma unroll
        for (int c = 0; c < 4; ++c) {
            bf16x8_t fb = *(const bf16x8_t*)(Bc + boff[c]);
#pragma unroll
            for (int t = 0; t < 8; ++t)
                acc[t][c] = __builtin_amdgcn_mfma_f32_16x16x32_bf16(fa[t], fb, acc[t][c], 0, 0, 0);
        }
        __builtin_amdgcn_s_setprio(0);
    }
#undef STAGE_TILE

    // epilogue: in-register partial LSE.
    // C layout: row = 128*wr + 16*t + 4*q + i, col = 64*wc + 16*c + lm
    float adjv[4]; int sidv[4]; bool cval[4];
#pragma unroll
    for (int c = 0; c < 4; ++c) {
        const int col = 64 * wc + 16 * c + lm;
        adjv[c] = adj_lds[col];
        sidv[c] = sid_lds[col];
        cval[c] = (chunk * 256 + col) < NSAMP;
    }
#pragma unroll
    for (int t = 0; t < 8; ++t) {
#pragma unroll
        for (int i = 0; i < 4; ++i) {
            const int r = 128 * wr + 16 * t + 4 * q + i;
            const int lab = lab_lds[r];
            float x[4]; bool ok[4];
            float m = -INFINITY;
#pragma unroll
            for (int c = 0; c < 4; ++c) {
                x[c] = acc[t][c][i] + adjv[c];
                ok[c] = cval[c] && (sidv[c] != lab);
                if (ok[c]) m = fmaxf(m, x[c]);
            }
            float ls = 0.0f;
#pragma unroll
            for (int c = 0; c < 4; ++c) ls += ok[c] ? __expf(x[c] - m) : 0.0f;
            // merge (m,l) across the 16 lanes holding this row's columns
#pragma unroll
            for (int off = 1; off < 16; off <<= 1) {
                const float mo = __shfl_xor(m, off, 64);
                const float lo = __shfl_xor(ls, off, 64);
                const float M  = fmaxf(m, mo);
                const float e1 = (ls > 0.0f) ? ls * __expf(m - M) : 0.0f;
                const float e2 = (lo > 0.0f) ? lo * __expf(mo - M) : 0.0f;
                m = M; ls = e1 + e2;
            }
            if (lm == 0) { mpart[wc][r] = m; lpart[wc][r] = ls; }
        }
    }
    __syncthreads();
    if (tid < 256) {
        float m = -INFINITY, lsum = 0.0f;
#pragma unroll
        for (int p = 0; p < 4; ++p) {
            const float mp = mpart[p][tid];
            const float lp = lpart[p][tid];
            if (lp > 0.0f) {
                if (mp > m) { lsum = lsum * __expf(m - mp) + lp; m = mp; }
                else        { lsum += lp * __expf(mp - m); }
            }
        }
        const int idx = (bb * SEQLEN + t0 + tid) * NCHUNK + chunk;
        pm[idx] = m;
        pl[idx] = lsum;
    }
}

// ---- combine: merge 4 partial (m,l) + true logit -> per-block loss sums ----
__global__ __launch_bounds__(256) void combine_kernel(
    const float* __restrict__ pm, const float* __restrict__ pl,
    const float* __restrict__ tlw, float* __restrict__ bsum)
{
    __shared__ float wsum[4];
    const int tid = threadIdx.x;
    const int w = tid >> 6, lane = tid & 63;
    const int idx = blockIdx.x * 256 + tid;      // 0..16383
    float m = -INFINITY, l = 0.0f;
#pragma unroll
    for (int c = 0; c < NCHUNK; ++c) {
        const float mp = pm[idx * NCHUNK + c];
        const float lp = pl[idx * NCHUNK + c];
        if (lp > 0.0f) {
            if (mp > m) { l = l * __expf(m - mp) + lp; m = mp; }
            else        { l += lp * __expf(mp - m); }
        }
    }
    const float t = tlw[idx];
    const float M = fmaxf(m, t);
    float loss = __logf(l * __expf(m - M) + __expf(t - M)) + M - t;
#pragma unroll
    for (int off = 32; off > 0; off >>= 1) loss += __shfl_xor(loss, off, 64);
    if (lane == 0) wsum[w] = loss;
    __syncthreads();
    if (tid == 0) bsum[blockIdx.x] = wsum[0] + wsum[1] + wsum[2] + wsum[3];
}

__global__ void finalize_kernel(const float* __restrict__ bsum, float* __restrict__ out) {
    float v = bsum[threadIdx.x];
#pragma unroll
    for (int off = 32; off > 0; off >>= 1) v += __shfl_xor(v, off, 64);
    if (threadIdx.x == 0) out[0] = v * (0.5f / (float)(BATCH * SEQLEN));
}

extern "C" void kernel_launch(void* const* d_in, const int* in_sizes, int n_in,
                              void* d_out, int out_size, void* d_ws, size_t ws_size,
                              hipStream_t stream) {
    const float* h      = (const float*)d_in[0];
    const int*   labels = (const int*)d_in[1];
    const int*   sids   = (const int*)d_in[2];
    const float* W      = (const float*)d_in[3];
    const float* bias   = (const float*)d_in[4];

    // workspace layout (~99.8 MB, 16B-aligned offsets)
    char* base = (char*)d_ws;
    unsigned short* Wb = (unsigned short*)base;                 // 65,536,000
    unsigned short* hb = (unsigned short*)(base + 65536000);    // 33,554,432
    float* adjw = (float*)(base + 99090432);                    //    128,000
    float* tlw  = (float*)(base + 99218432);                    //     65,536
    float* pmw  = (float*)(base + 99283968);                    //    262,144
    float* plw  = (float*)(base + 99546112);                    //    262,144
    float* bsum = (float*)(base + 99808256);                    //        256

    prep_kernel<<<dim3(12096), dim3(256), 0, stream>>>(h, labels, sids, W, bias, Wb, hb, adjw, tlw);
    sampled_softmax_main<<<dim3(256), dim3(512), 0, stream>>>(
        labels, sids, hb, Wb, adjw, pmw, plw);
    combine_kernel<<<dim3(64), dim3(256), 0, stream>>>(pmw, plw, tlw, bsum);
    finalize_kernel<<<dim3(1), dim3(64), 0, stream>>>(bsum, (float*)d_out);
}

// Round 5
// 384.932 us; speedup vs baseline: 1.0775x; 1.0256x over previous
//
#include <hip/hip_runtime.h>
#include <cmath>

#define BATCH 32
#define SEQLEN 512
#define NSAMP 1000
#define DMODEL 1024
#define NCHUNK 4

typedef __bf16 bf16x8_t __attribute__((ext_vector_type(8)));
typedef float f32x4_t __attribute__((ext_vector_type(4)));

__device__ __forceinline__ unsigned pack_bf2(float lo, float hi) {
    unsigned ulo = __float_as_uint(lo);
    unsigned uhi = __float_as_uint(hi);
    ulo = (ulo + 0x7fffu + ((ulo >> 16) & 1u)) >> 16;
    uhi = (uhi + 0x7fffu + ((uhi >> 16) & 1u)) & 0xffff0000u;
    return (ulo & 0xffffu) | uhi;
}

// TF log-uniform sampler expected-count, log-domain
__device__ __forceinline__ float log_expected_count(int id) {
    float idf = (float)id;
    float p = log1pf(1.0f / (idf + 1.0f)) * 0.09242316f; // 1/ln(50001)
    return logf(-expm1f(1000.0f * log1pf(-p)));
}

// async 16B global->LDS (dest = wave-uniform base + lane*16)
__device__ __forceinline__ void gl16(const void* g, void* l) {
    __builtin_amdgcn_global_load_lds(
        (const __attribute__((address_space(1))) unsigned int*)g,
        (__attribute__((address_space(3))) unsigned int*)l,
        16, 0, 0);
}

// ---- prep: W-row gather->bf16 (+adj), fp32 true-logit dot, and h->bf16 ----
__global__ __launch_bounds__(256) void prep_kernel(
    const float* __restrict__ h, const int* __restrict__ labels,
    const int* __restrict__ sids, const float* __restrict__ W,
    const float* __restrict__ bias, unsigned short* __restrict__ Wb,
    unsigned short* __restrict__ hb,
    float* __restrict__ adjw, float* __restrict__ tlw)
{
    const int w = threadIdx.x >> 6, lane = threadIdx.x & 63;
    if (blockIdx.x < 8000) {
        const int row = blockIdx.x * 4 + w;            // b*1000+s
        const int sv = sids[row];
        const float4* src = (const float4*)(W + (size_t)sv * DMODEL);
        unsigned short* dst = Wb + (size_t)row * DMODEL;
#pragma unroll
        for (int j = 0; j < 4; ++j) {
            float4 v = src[lane + j * 64];
            uint2 u;
            u.x = pack_bf2(v.x, v.y);
            u.y = pack_bf2(v.z, v.w);
            *(uint2*)(dst + (lane + j * 64) * 4) = u;
        }
        if (lane == 0) adjw[row] = bias[sv] - log_expected_count(sv);
    } else {
        const int r = (blockIdx.x - 8000) * 4 + w;     // b*512+t
        const int lab = labels[r];
        const float4* hp = (const float4*)(h + (size_t)r * DMODEL);
        const float4* wp = (const float4*)(W + (size_t)lab * DMODEL);
        unsigned short* hdst = hb + (size_t)r * DMODEL;
        float s = 0.0f;
#pragma unroll
        for (int j = 0; j < 4; ++j) {
            float4 a = hp[lane + j * 64];
            float4 c = wp[lane + j * 64];
            s += a.x * c.x + a.y * c.y + a.z * c.z + a.w * c.w;
            uint2 u;
            u.x = pack_bf2(a.x, a.y);
            u.y = pack_bf2(a.z, a.w);
            *(uint2*)(hdst + (lane + j * 64) * 4) = u;
        }
#pragma unroll
        for (int off = 32; off > 0; off >>= 1) s += __shfl_xor(s, off, 64);
        if (lane == 0) tlw[r] = s + bias[lab] - log_expected_count(lab);
    }
}

// ---- main: 256x256 tile, BK=64, 16 K-iterations, 2-buffer pipeline ----
// Discriminating experiment: same traffic (265 MB) as BK=32 version but
// HALF the barriers/vmcnt waits; ~2060 cyc of MFMA between syncs; stage
// (kt+2) issued a full iteration before its vmcnt(8) wait.
// LDS rows are 64 elems (128 B); chunk swizzle: global chunk g of row r
// stored at position g ^ (r&7) -> frag ds_read_b128 is 2-way (free).
__global__ __launch_bounds__(512, 2) void sampled_softmax_main(
    const int* __restrict__ labels, const int* __restrict__ sids,
    const unsigned short* __restrict__ hb, const unsigned short* __restrict__ Wb,
    const float* __restrict__ adjw,
    float* __restrict__ pm, float* __restrict__ pl)
{
    __shared__ __align__(16) unsigned short Ab[2][256 * 64];   // 64 KB
    __shared__ __align__(16) unsigned short Bb[2][256 * 64];   // 64 KB
    __shared__ int   sid_lds[256];
    __shared__ float adj_lds[256];
    __shared__ int   lab_lds[256];
    __shared__ float mpart[4][256];
    __shared__ float lpart[4][256];

    const int wg     = blockIdx.x;       // 0..255
    const int bb     = wg & 31;          // same-bb blocks share XCD (wg%8)
    const int rest   = wg >> 5;          // 0..7
    const int tile_t = rest & 1;         // 0..1
    const int chunk  = rest >> 1;        // 0..3
    const int t0  = tile_t * 256;
    const int tid = threadIdx.x;
    const int wv  = tid >> 6, l = tid & 63;
    const int wr  = wv >> 2, wc = wv & 3;   // 2x4 wave grid
    const int lm  = l & 15,  q = l >> 4;
    const int rl8 = l >> 3,  cp8 = l & 7;

    if (tid < 256) {   // block-level index/adj staging (read only in epilogue)
        const int s = chunk * 256 + tid;
        const bool v = s < NSAMP;
        sid_lds[tid] = v ? sids[bb * NSAMP + s] : -1;
        adj_lds[tid] = v ? adjw[bb * NSAMP + s] : 0.0f;
        lab_lds[tid] = labels[bb * SEQLEN + t0 + tid];
    }

    // staging: linear LDS dest, inverse-swizzled global source (rule #21).
    // Thread supplies chunk cp8 of LDS row (32*wv + 8*j + rl8); global
    // source chunk = cp8 ^ (row&7) = cp8 ^ rl8 (8j, 32wv are 0 mod 8).
    const int csg = (cp8 ^ rl8) * 8;                   // elem offset in 64-slab
    const unsigned short* aSrc = hb + (size_t)(bb * SEQLEN + t0 + 32 * wv + rl8) * DMODEL + csg;
    const unsigned short* bSrc[4];
#pragma unroll
    for (int j = 0; j < 4; ++j) {
        int rb = chunk * 256 + 32 * wv + 8 * j + rl8;
        if (rb > NSAMP - 1) rb = NSAMP - 1;            // clamp (masked in LSE)
        bSrc[j] = Wb + (size_t)(bb * NSAMP + rb) * DMODEL + csg;
    }

#define STAGE_TILE(KT, BUF)                                                   \
    do {                                                                      \
        const size_t _adv = (size_t)(KT) * 64;                                \
        gl16(aSrc + _adv,                 &Ab[BUF][(32 * wv     ) * 64]);     \
        gl16(aSrc + 8 * DMODEL + _adv,    &Ab[BUF][(32 * wv +  8) * 64]);     \
        gl16(aSrc + 16 * DMODEL + _adv,   &Ab[BUF][(32 * wv + 16) * 64]);     \
        gl16(aSrc + 24 * DMODEL + _adv,   &Ab[BUF][(32 * wv + 24) * 64]);     \
        gl16(bSrc[0] + _adv, &Bb[BUF][(32 * wv     ) * 64]);                  \
        gl16(bSrc[1] + _adv, &Bb[BUF][(32 * wv +  8) * 64]);                  \
        gl16(bSrc[2] + _adv, &Bb[BUF][(32 * wv + 16) * 64]);                  \
        gl16(bSrc[3] + _adv, &Bb[BUF][(32 * wv + 24) * 64]);                  \
    } while (0)

    // fragment read offsets: row part + swizzled chunk part (2 ksubs)
    const int ck0 = ((0 + q) ^ (lm & 7)) * 8;
    const int ck1 = ((4 + q) ^ (lm & 7)) * 8;
    int rowA[8], rowB[4];
#pragma unroll
    for (int t = 0; t < 8; ++t) rowA[t] = (128 * wr + 16 * t + lm) * 64;
#pragma unroll
    for (int c = 0; c < 4; ++c) rowB[c] = (64 * wc + 16 * c + lm) * 64;

    f32x4_t acc[8][4];
#pragma unroll
    for (int t = 0; t < 8; ++t)
#pragma unroll
        for (int c = 0; c < 4; ++c) acc[t][c] = (f32x4_t){0.f, 0.f, 0.f, 0.f};

    // prologue: tiles 0 and 1 in flight (16 loads/thread), no vm drain.
    STAGE_TILE(0, 0);
    STAGE_TILE(1, 1);
    // make sid/adj/lab ds_writes visible; lgkmcnt does NOT touch vmcnt.
    asm volatile("s_waitcnt lgkmcnt(0)" ::: "memory");
    __builtin_amdgcn_s_barrier();

#pragma unroll
    for (int kt = 0; kt < 16; ++kt) {
        // tile kt landed (oldest 8 of 16 outstanding retired); kt+1 stays in flight
        if (kt < 15) { asm volatile("s_waitcnt vmcnt(8)" ::: "memory"); }
        else         { asm volatile("s_waitcnt vmcnt(0)" ::: "memory"); }
        __builtin_amdgcn_s_barrier();

        const unsigned short* Ac = Ab[kt & 1];
        const unsigned short* Bc = Bb[kt & 1];
#pragma unroll
        for (int s = 0; s < 2; ++s) {
            const int ck = s ? ck1 : ck0;
            bf16x8_t fa[8];
#pragma unroll
            for (int t = 0; t < 8; ++t) fa[t] = *(const bf16x8_t*)(Ac + rowA[t] + ck);
            __builtin_amdgcn_s_setprio(1);
#pragma unroll
            for (int c = 0; c < 4; ++c) {
                bf16x8_t fb = *(const bf16x8_t*)(Bc + rowB[c] + ck);
#pragma unroll
                for (int t = 0; t < 8; ++t)
                    acc[t][c] = __builtin_amdgcn_mfma_f32_16x16x32_bf16(fa[t], fb, acc[t][c], 0, 0, 0);
            }
            __builtin_amdgcn_s_setprio(0);
        }

        if (kt + 2 < 16) {
            // all waves done reading buf (kt&1) for this kt -> safe to overwrite
            __builtin_amdgcn_s_barrier();
            STAGE_TILE(kt + 2, kt & 1);
        }
    }
#undef STAGE_TILE

    // epilogue: in-register partial LSE.
    // C layout: row = 128*wr + 16*t + 4*q + i, col = 64*wc + 16*c + lm
    float adjv[4]; int sidv[4]; bool cval[4];
#pragma unroll
    for (int c = 0; c < 4; ++c) {
        const int col = 64 * wc + 16 * c + lm;
        adjv[c] = adj_lds[col];
        sidv[c] = sid_lds[col];
        cval[c] = (chunk * 256 + col) < NSAMP;
    }
#pragma unroll
    for (int t = 0; t < 8; ++t) {
#pragma unroll
        for (int i = 0; i < 4; ++i) {
            const int r = 128 * wr + 16 * t + 4 * q + i;
            const int lab = lab_lds[r];
            float x[4]; bool ok[4];
            float m = -INFINITY;
#pragma unroll
            for (int c = 0; c < 4; ++c) {
                x[c] = acc[t][c][i] + adjv[c];
                ok[c] = cval[c] && (sidv[c] != lab);
                if (ok[c]) m = fmaxf(m, x[c]);
            }
            float ls = 0.0f;
#pragma unroll
            for (int c = 0; c < 4; ++c) ls += ok[c] ? __expf(x[c] - m) : 0.0f;
            // merge (m,l) across the 16 lanes holding this row's columns
#pragma unroll
            for (int off = 1; off < 16; off <<= 1) {
                const float mo = __shfl_xor(m, off, 64);
                const float lo = __shfl_xor(ls, off, 64);
                const float M  = fmaxf(m, mo);
                const float e1 = (ls > 0.0f) ? ls * __expf(m - M) : 0.0f;
                const float e2 = (lo > 0.0f) ? lo * __expf(mo - M) : 0.0f;
                m = M; ls = e1 + e2;
            }
            if (lm == 0) { mpart[wc][r] = m; lpart[wc][r] = ls; }
        }
    }
    __syncthreads();
    if (tid < 256) {
        float m = -INFINITY, lsum = 0.0f;
#pragma unroll
        for (int p = 0; p < 4; ++p) {
            const float mp = mpart[p][tid];
            const float lp = lpart[p][tid];
            if (lp > 0.0f) {
                if (mp > m) { lsum = lsum * __expf(m - mp) + lp; m = mp; }
                else        { lsum += lp * __expf(mp - m); }
            }
        }
        const int idx = (bb * SEQLEN + t0 + tid) * NCHUNK + chunk;
        pm[idx] = m;
        pl[idx] = lsum;
    }
}

// ---- combine: merge 4 partial (m,l) + true logit -> per-block loss sums ----
__global__ __launch_bounds__(256) void combine_kernel(
    const float* __restrict__ pm, const float* __restrict__ pl,
    const float* __restrict__ tlw, float* __restrict__ bsum)
{
    __shared__ float wsum[4];
    const int tid = threadIdx.x;
    const int w = tid >> 6, lane = tid & 63;
    const int idx = blockIdx.x * 256 + tid;      // 0..16383
    float m = -INFINITY, l = 0.0f;
#pragma unroll
    for (int c = 0; c < NCHUNK; ++c) {
        const float mp = pm[idx * NCHUNK + c];
        const float lp = pl[idx * NCHUNK + c];
        if (lp > 0.0f) {
            if (mp > m) { l = l * __expf(m - mp) + lp; m = mp; }
            else        { l += lp * __expf(mp - m); }
        }
    }
    const float t = tlw[idx];
    const float M = fmaxf(m, t);
    float loss = __logf(l * __expf(m - M) + __expf(t - M)) + M - t;
#pragma unroll
    for (int off = 32; off > 0; off >>= 1) loss += __shfl_xor(loss, off, 64);
    if (lane == 0) wsum[w] = loss;
    __syncthreads();
    if (tid == 0) bsum[blockIdx.x] = wsum[0] + wsum[1] + wsum[2] + wsum[3];
}

__global__ void finalize_kernel(const float* __restrict__ bsum, float* __restrict__ out) {
    float v = bsum[threadIdx.x];
#pragma unroll
    for (int off = 32; off > 0; off >>= 1) v += __shfl_xor(v, off, 64);
    if (threadIdx.x == 0) out[0] = v * (0.5f / (float)(BATCH * SEQLEN));
}

extern "C" void kernel_launch(void* const* d_in, const int* in_sizes, int n_in,
                              void* d_out, int out_size, void* d_ws, size_t ws_size,
                              hipStream_t stream) {
    const float* h      = (const float*)d_in[0];
    const int*   labels = (const int*)d_in[1];
    const int*   sids   = (const int*)d_in[2];
    const float* W      = (const float*)d_in[3];
    const float* bias   = (const float*)d_in[4];

    // workspace layout (~99.8 MB, 16B-aligned offsets)
    char* base = (char*)d_ws;
    unsigned short* Wb = (unsigned short*)base;                 // 65,536,000
    unsigned short* hb = (unsigned short*)(base + 65536000);    // 33,554,432
    float* adjw = (float*)(base + 99090432);                    //    128,000
    float* tlw  = (float*)(base + 99218432);                    //     65,536
    float* pmw  = (float*)(base + 99283968);                    //    262,144
    float* plw  = (float*)(base + 99546112);                    //    262,144
    float* bsum = (float*)(base + 99808256);                    //        256

    prep_kernel<<<dim3(12096), dim3(256), 0, stream>>>(h, labels, sids, W, bias, Wb, hb, adjw, tlw);
    sampled_softmax_main<<<dim3(256), dim3(512), 0, stream>>>(
        labels, sids, hb, Wb, adjw, pmw, plw);
    combine_kernel<<<dim3(64), dim3(256), 0, stream>>>(pmw, plw, tlw, bsum);
    finalize_kernel<<<dim3(1), dim3(64), 0, stream>>>(bsum, (float*)d_out);
}

// Round 6
// 375.173 us; speedup vs baseline: 1.1055x; 1.0260x over previous
//
#include <hip/hip_runtime.h>
#include <cmath>

#define BATCH 32
#define SEQLEN 512
#define NSAMP 1000
#define DMODEL 1024
#define NCHUNK 4

typedef __bf16 bf16x8_t __attribute__((ext_vector_type(8)));
typedef float f32x4_t __attribute__((ext_vector_type(4)));

__device__ __forceinline__ unsigned pack_bf2(float lo, float hi) {
    unsigned ulo = __float_as_uint(lo);
    unsigned uhi = __float_as_uint(hi);
    ulo = (ulo + 0x7fffu + ((ulo >> 16) & 1u)) >> 16;
    uhi = (uhi + 0x7fffu + ((uhi >> 16) & 1u)) & 0xffff0000u;
    return (ulo & 0xffffu) | uhi;
}

// TF log-uniform sampler expected-count, log-domain
__device__ __forceinline__ float log_expected_count(int id) {
    float idf = (float)id;
    float p = log1pf(1.0f / (idf + 1.0f)) * 0.09242316f; // 1/ln(50001)
    return logf(-expm1f(1000.0f * log1pf(-p)));
}

// async 16B global->LDS (dest = wave-uniform base + lane*16)
__device__ __forceinline__ void gl16(const void* g, void* l) {
    __builtin_amdgcn_global_load_lds(
        (const __attribute__((address_space(1))) unsigned int*)g,
        (__attribute__((address_space(3))) unsigned int*)l,
        16, 0, 0);
}

// ---- prep: fp32 true-logit dot + h->bf16 conversion (Wb gather is fused
// into main now: W-row gather moved to main's B-staging path) ----
__global__ __launch_bounds__(256) void prep_kernel(
    const float* __restrict__ h, const int* __restrict__ labels,
    const float* __restrict__ W, const float* __restrict__ bias,
    unsigned short* __restrict__ hb, float* __restrict__ tlw)
{
    const int w = threadIdx.x >> 6, lane = threadIdx.x & 63;
    const int r = blockIdx.x * 4 + w;              // b*512+t
    const int lab = labels[r];
    const float4* hp = (const float4*)(h + (size_t)r * DMODEL);
    const float4* wp = (const float4*)(W + (size_t)lab * DMODEL);
    unsigned short* hdst = hb + (size_t)r * DMODEL;
    float s = 0.0f;
#pragma unroll
    for (int j = 0; j < 4; ++j) {
        float4 a = hp[lane + j * 64];
        float4 c = wp[lane + j * 64];
        s += a.x * c.x + a.y * c.y + a.z * c.z + a.w * c.w;
        uint2 u;
        u.x = pack_bf2(a.x, a.y);
        u.y = pack_bf2(a.z, a.w);
        *(uint2*)(hdst + (lane + j * 64) * 4) = u;
    }
#pragma unroll
    for (int off = 32; off > 0; off >>= 1) s += __shfl_xor(s, off, 64);
    if (lane == 0) tlw[r] = s + bias[lab] - log_expected_count(lab);
}

// ---- main: 256x256 tile, BK=64, fused W-gather->bf16 B-staging ----
// B path: reg-stage gathered fp32 W rows -> pack_bf2 -> swizzled ds_write
// (write swizzle == read swizzle involution: pos = chunk ^ (row&7)).
// A path: gl16 from hb (pre-swizzled source, linear dest).
// Per iter: issue B[kt+1] regs + A[kt+1] gl16 -> vmcnt(12) -> MFMA phase
// -> vmcnt(4) -> pack+ds_write B[kt+1] -> lgkm0 -> ONE barrier. Counted
// waits never drain mid-loop; tile_t pairs co-XCD for W-gather L2 reuse.
__global__ __launch_bounds__(512, 2) void sampled_softmax_main(
    const int* __restrict__ labels, const int* __restrict__ sids,
    const unsigned short* __restrict__ hb, const float* __restrict__ W,
    const float* __restrict__ bias,
    float* __restrict__ pm, float* __restrict__ pl)
{
    __shared__ __align__(16) unsigned short Ab[2][256 * 64];   // 64 KB
    __shared__ __align__(16) unsigned short Bb[2][256 * 64];   // 64 KB
    __shared__ int   sid_lds[256];
    __shared__ float adj_lds[256];
    __shared__ int   lab_lds[256];
    __shared__ float mpart[4][256];
    __shared__ float lpart[4][256];

    const int wg     = blockIdx.x;       // 0..255
    const int bb     = wg & 31;          // same-bb blocks share XCD (wg%8)
    const int rest   = wg >> 5;          // 0..7
    const int tile_t = rest & 1;         // 0..1  (pair differs by 32 in wg -> co-XCD)
    const int chunk  = rest >> 1;        // 0..3
    const int t0  = tile_t * 256;
    const int tid = threadIdx.x;
    const int wv  = tid >> 6, l = tid & 63;
    const int wr  = wv >> 2, wc = wv & 3;   // 2x4 wave grid
    const int lm  = l & 15,  q = l >> 4;
    const int rl8 = l >> 3,  cp8 = l & 7;

    if (tid < 256) {   // aux staging: sid/adj (fused bias+log_q) /labels
        const int s = chunk * 256 + tid;
        if (s < NSAMP) {
            const int sv = sids[bb * NSAMP + s];
            sid_lds[tid] = sv;
            adj_lds[tid] = bias[sv] - log_expected_count(sv);
        } else {
            sid_lds[tid] = -1;
            adj_lds[tid] = 0.0f;
        }
        lab_lds[tid] = labels[bb * SEQLEN + t0 + tid];
    }

    // A staging: linear LDS dest, inverse-swizzled global source (rule #21)
    const int csg = (cp8 ^ rl8) * 8;
    const unsigned short* aSrc = hb + (size_t)(bb * SEQLEN + t0 + 32 * wv + rl8) * DMODEL + csg;

    // B staging: per thread 4 rows r_j = 32*wv + 8*j + rl8; source = W row
    // sids[rb] at k-chunk cp8 (8 fp32); dest = swizzled pos cp8 ^ rl8.
    const float* wsrc[4];
    int bwoff[4];
#pragma unroll
    for (int j = 0; j < 4; ++j) {
        int rb = chunk * 256 + 32 * wv + 8 * j + rl8;
        if (rb > NSAMP - 1) rb = NSAMP - 1;            // clamp (masked in LSE)
        const int sv = sids[bb * NSAMP + rb];
        wsrc[j] = W + (size_t)sv * DMODEL + cp8 * 8;
        bwoff[j] = (32 * wv + 8 * j + rl8) * 64 + (cp8 ^ rl8) * 8;
    }

    float4 br[8];
#define LOAD_B(KT)                                                            \
    do {                                                                      \
        br[0] = *(const float4*)(wsrc[0] + (KT) * 64);                        \
        br[1] = *(const float4*)(wsrc[0] + (KT) * 64 + 4);                    \
        br[2] = *(const float4*)(wsrc[1] + (KT) * 64);                        \
        br[3] = *(const float4*)(wsrc[1] + (KT) * 64 + 4);                    \
        br[4] = *(const float4*)(wsrc[2] + (KT) * 64);                        \
        br[5] = *(const float4*)(wsrc[2] + (KT) * 64 + 4);                    \
        br[6] = *(const float4*)(wsrc[3] + (KT) * 64);                        \
        br[7] = *(const float4*)(wsrc[3] + (KT) * 64 + 4);                    \
    } while (0)

#define PACK_WRITE_B(BUF)                                                     \
    do {                                                                      \
        _Pragma("unroll")                                                     \
        for (int j = 0; j < 4; ++j) {                                         \
            uint4 u;                                                          \
            u.x = pack_bf2(br[2 * j].x, br[2 * j].y);                         \
            u.y = pack_bf2(br[2 * j].z, br[2 * j].w);                         \
            u.z = pack_bf2(br[2 * j + 1].x, br[2 * j + 1].y);                 \
            u.w = pack_bf2(br[2 * j + 1].z, br[2 * j + 1].w);                 \
            *(uint4*)&Bb[BUF][bwoff[j]] = u;                                  \
        }                                                                     \
    } while (0)

#define STAGE_A(KT, BUF)                                                      \
    do {                                                                      \
        const size_t _adv = (size_t)(KT) * 64;                                \
        gl16(aSrc + _adv,               &Ab[BUF][(32 * wv     ) * 64]);       \
        gl16(aSrc + 8 * DMODEL + _adv,  &Ab[BUF][(32 * wv +  8) * 64]);       \
        gl16(aSrc + 16 * DMODEL + _adv, &Ab[BUF][(32 * wv + 16) * 64]);       \
        gl16(aSrc + 24 * DMODEL + _adv, &Ab[BUF][(32 * wv + 24) * 64]);       \
    } while (0)

    // fragment read offsets: row part + swizzled chunk part (2 ksubs)
    const int ck0 = ((0 + q) ^ (lm & 7)) * 8;
    const int ck1 = ((4 + q) ^ (lm & 7)) * 8;
    int rowA[8], rowB[4];
#pragma unroll
    for (int t = 0; t < 8; ++t) rowA[t] = (128 * wr + 16 * t + lm) * 64;
#pragma unroll
    for (int c = 0; c < 4; ++c) rowB[c] = (64 * wc + 16 * c + lm) * 64;

    f32x4_t acc[8][4];
#pragma unroll
    for (int t = 0; t < 8; ++t)
#pragma unroll
        for (int c = 0; c < 4; ++c) acc[t][c] = (f32x4_t){0.f, 0.f, 0.f, 0.f};

    // prologue: tile 0 fully staged (A via gl16, B via reg+pack)
    LOAD_B(0);
    __builtin_amdgcn_sched_barrier(0);   // keep B-loads before gl16s (vmcnt order)
    STAGE_A(0, 0);
    asm volatile("s_waitcnt vmcnt(0)" ::: "memory");
    PACK_WRITE_B(0);
    asm volatile("s_waitcnt lgkmcnt(0)" ::: "memory");
    __builtin_amdgcn_s_barrier();

#pragma unroll
    for (int kt = 0; kt < 16; ++kt) {
        const int cur = kt & 1, nxt = cur ^ 1;
        if (kt + 1 < 16) {
            LOAD_B(kt + 1);                         // [B x8] then [A x4] in vmcnt order
            __builtin_amdgcn_sched_barrier(0);
            STAGE_A(kt + 1, nxt);
            // drain everything older than this iter's 12 -> A[kt] landed in cur
            asm volatile("s_waitcnt vmcnt(12)" ::: "memory");
        } else {
            asm volatile("s_waitcnt vmcnt(0)" ::: "memory");
        }

        const unsigned short* Ac = Ab[cur];
        const unsigned short* Bc = Bb[cur];
#pragma unroll
        for (int s = 0; s < 2; ++s) {
            const int ck = s ? ck1 : ck0;
            bf16x8_t fa[8];
#pragma unroll
            for (int t = 0; t < 8; ++t) fa[t] = *(const bf16x8_t*)(Ac + rowA[t] + ck);
            __builtin_amdgcn_s_setprio(1);
#pragma unroll
            for (int c = 0; c < 4; ++c) {
                bf16x8_t fb = *(const bf16x8_t*)(Bc + rowB[c] + ck);
#pragma unroll
                for (int t = 0; t < 8; ++t)
                    acc[t][c] = __builtin_amdgcn_mfma_f32_16x16x32_bf16(fa[t], fb, acc[t][c], 0, 0, 0);
            }
            __builtin_amdgcn_s_setprio(0);
        }

        if (kt + 1 < 16) {
            // B[kt+1] regs landed (A[kt+1] gl16 x4 may stay in flight)
            asm volatile("s_waitcnt vmcnt(4)" ::: "memory");
            PACK_WRITE_B(nxt);
            asm volatile("s_waitcnt lgkmcnt(0)" ::: "memory");
            __builtin_amdgcn_s_barrier();   // ONE barrier per iteration
        }
    }
#undef LOAD_B
#undef PACK_WRITE_B
#undef STAGE_A

    // epilogue: in-register partial LSE.
    // C layout: row = 128*wr + 16*t + 4*q + i, col = 64*wc + 16*c + lm
    float adjv[4]; int sidv[4]; bool cval[4];
#pragma unroll
    for (int c = 0; c < 4; ++c) {
        const int col = 64 * wc + 16 * c + lm;
        adjv[c] = adj_lds[col];
        sidv[c] = sid_lds[col];
        cval[c] = (chunk * 256 + col) < NSAMP;
    }
#pragma unroll
    for (int t = 0; t < 8; ++t) {
#pragma unroll
        for (int i = 0; i < 4; ++i) {
            const int r = 128 * wr + 16 * t + 4 * q + i;
            const int lab = lab_lds[r];
            float x[4]; bool ok[4];
            float m = -INFINITY;
#pragma unroll
            for (int c = 0; c < 4; ++c) {
                x[c] = acc[t][c][i] + adjv[c];
                ok[c] = cval[c] && (sidv[c] != lab);
                if (ok[c]) m = fmaxf(m, x[c]);
            }
            float ls = 0.0f;
#pragma unroll
            for (int c = 0; c < 4; ++c) ls += ok[c] ? __expf(x[c] - m) : 0.0f;
            // merge (m,l) across the 16 lanes holding this row's columns
#pragma unroll
            for (int off = 1; off < 16; off <<= 1) {
                const float mo = __shfl_xor(m, off, 64);
                const float lo = __shfl_xor(ls, off, 64);
                const float M  = fmaxf(m, mo);
                const float e1 = (ls > 0.0f) ? ls * __expf(m - M) : 0.0f;
                const float e2 = (lo > 0.0f) ? lo * __expf(mo - M) : 0.0f;
                m = M; ls = e1 + e2;
            }
            if (lm == 0) { mpart[wc][r] = m; lpart[wc][r] = ls; }
        }
    }
    __syncthreads();
    if (tid < 256) {
        float m = -INFINITY, lsum = 0.0f;
#pragma unroll
        for (int p = 0; p < 4; ++p) {
            const float mp = mpart[p][tid];
            const float lp = lpart[p][tid];
            if (lp > 0.0f) {
                if (mp > m) { lsum = lsum * __expf(m - mp) + lp; m = mp; }
                else        { lsum += lp * __expf(mp - m); }
            }
        }
        const int idx = (bb * SEQLEN + t0 + tid) * NCHUNK + chunk;
        pm[idx] = m;
        pl[idx] = lsum;
    }
}

// ---- combine: merge 4 partial (m,l) + true logit -> per-block loss sums ----
__global__ __launch_bounds__(256) void combine_kernel(
    const float* __restrict__ pm, const float* __restrict__ pl,
    const float* __restrict__ tlw, float* __restrict__ bsum)
{
    __shared__ float wsum[4];
    const int tid = threadIdx.x;
    const int w = tid >> 6, lane = tid & 63;
    const int idx = blockIdx.x * 256 + tid;      // 0..16383
    float m = -INFINITY, l = 0.0f;
#pragma unroll
    for (int c = 0; c < NCHUNK; ++c) {
        const float mp = pm[idx * NCHUNK + c];
        const float lp = pl[idx * NCHUNK + c];
        if (lp > 0.0f) {
            if (mp > m) { l = l * __expf(m - mp) + lp; m = mp; }
            else        { l += lp * __expf(mp - m); }
        }
    }
    const float t = tlw[idx];
    const float M = fmaxf(m, t);
    float loss = __logf(l * __expf(m - M) + __expf(t - M)) + M - t;
#pragma unroll
    for (int off = 32; off > 0; off >>= 1) loss += __shfl_xor(loss, off, 64);
    if (lane == 0) wsum[w] = loss;
    __syncthreads();
    if (tid == 0) bsum[blockIdx.x] = wsum[0] + wsum[1] + wsum[2] + wsum[3];
}

__global__ void finalize_kernel(const float* __restrict__ bsum, float* __restrict__ out) {
    float v = bsum[threadIdx.x];
#pragma unroll
    for (int off = 32; off > 0; off >>= 1) v += __shfl_xor(v, off, 64);
    if (threadIdx.x == 0) out[0] = v * (0.5f / (float)(BATCH * SEQLEN));
}

extern "C" void kernel_launch(void* const* d_in, const int* in_sizes, int n_in,
                              void* d_out, int out_size, void* d_ws, size_t ws_size,
                              hipStream_t stream) {
    const float* h      = (const float*)d_in[0];
    const int*   labels = (const int*)d_in[1];
    const int*   sids   = (const int*)d_in[2];
    const float* W      = (const float*)d_in[3];
    const float* bias   = (const float*)d_in[4];

    // workspace layout (~34.2 MB, 16B-aligned offsets)
    char* base = (char*)d_ws;
    unsigned short* hb = (unsigned short*)base;                 // 33,554,432
    float* tlw  = (float*)(base + 33554432);                    //     65,536
    float* pmw  = (float*)(base + 33619968);                    //    262,144
    float* plw  = (float*)(base + 33882112);                    //    262,144
    float* bsum = (float*)(base + 34144256);                    //        256

    prep_kernel<<<dim3(4096), dim3(256), 0, stream>>>(h, labels, W, bias, hb, tlw);
    sampled_softmax_main<<<dim3(256), dim3(512), 0, stream>>>(
        labels, sids, hb, W, bias, pmw, plw);
    combine_kernel<<<dim3(64), dim3(256), 0, stream>>>(pmw, plw, tlw, bsum);
    finalize_kernel<<<dim3(1), dim3(64), 0, stream>>>(bsum, (float*)d_out);
}